// Round 4
// baseline (20.913 us; speedup 1.0000x reference)
//
#include <hip/hip_runtime.h>
#include <math.h>

// DSS "softmax" kernel: K[c,h,l] = Re( sum_n Wc[c,h,n] * exp(z[h,n]*(l - loff)) )
// Round 4: two-kernel structure.
//   Kernel A: per-(h,n) coefficients in f64 (one thread each) -> d_ws.
//   Kernel B: Chebyshev 3-term recurrence along l, n-loop split 2-way across
//   a 512-thread block (lanes 0-255: n in [0,32), lanes 256-511: n in [32,64)),
//   partials combined via LDS. 4 waves/SIMD instead of 2 -> latency hiding.

#if __has_builtin(__builtin_amdgcn_sinf)
__device__ inline float vsin_rev(float x) { return __builtin_amdgcn_sinf(x); }   // sin(2*pi*x)
__device__ inline float vcos_rev(float x) { return __builtin_amdgcn_cosf(x); }   // cos(2*pi*x)
#else
__device__ inline float vsin_rev(float x) { return __sinf(x * 6.28318530717958647692f); }
__device__ inline float vcos_rev(float x) { return __cosf(x * 6.28318530717958647692f); }
#endif

typedef float v2f __attribute__((ext_vector_type(2)));

#define KPT   8      // l-values per thread
#define TPB_L 256    // threads per l-slice
#define NSPLIT 2     // n-groups per block
#define TPB   (TPB_L * NSPLIT)

// ---------------- Kernel A: coefficient prep (f64) ----------------
__global__ __launch_bounds__(256) void dss_prep(
    const float* __restrict__ Lambda,   // [N,2]
    const float* __restrict__ log_dt,   // [H,2]
    const float* __restrict__ W,        // [C,H,N,2]
    float4* __restrict__ ws,            // [C,H,3,N] float4: A,B,Cc
    int H, int N, int L, int C)
{
    int idx = blockIdx.x * blockDim.x + threadIdx.x;
    int total = C * H * N;
    if (idx >= total) return;
    int n = idx % N;
    int hc = idx / N;       // c*H + h
    int h = hc % H;

    double dt0 = exp((double)log_dt[h*2 + 0]);
    double dt1 = exp((double)log_dt[h*2 + 1]);
    double lre = (double)Lambda[n*2 + 0];
    double lim = (double)Lambda[n*2 + 1];
    double zr = dt0 * lre;
    double zi = dt1 * lim;
    bool gt0 = (lre > 0.0);
    double sgn = gt0 ? -1.0 : 1.0;
    double dnr = sgn * zr, dni = sgn * zi;
    // num = exp(dn) - 1
    double ednr  = exp(dnr);
    double num_re = ednr * cos(dni) - 1.0;
    double num_im = ednr * sin(dni);
    // den = exp(L*dn) - 1
    double Ld = (double)L;
    double eLr = exp(Ld * dnr);
    double den_re = eLr * cos(Ld * dni) - 1.0;
    double den_im = eLr * sin(Ld * dni);
    // x = den * Lam ; recip = conj(x)/(|x|^2 + eps)
    double x_re = den_re * lre - den_im * lim;
    double x_im = den_re * lim + den_im * lre;
    double inv  = 1.0 / (x_re*x_re + x_im*x_im + 1e-7);
    double r_re =  x_re * inv;
    double r_im = -x_im * inv;
    // m = num * recip
    double m_re = num_re * r_re - num_im * r_im;
    double m_im = num_re * r_im + num_im * r_re;
    // Wc = (W0 + i*W1) * m
    double w0 = (double)W[(size_t)idx*2 + 0];
    double w1 = (double)W[(size_t)idx*2 + 1];
    double wr = w0 * m_re - w1 * m_im;
    double wi = w0 * m_im + w1 * m_re;
    double loff = gt0 ? (double)(L - 1) : 0.0;

    const double LOG2E  = 1.4426950408889634074;
    const double INV2PI = 0.15915494309189533577;
    double er = zr * LOG2E;
    double ph = zi * INV2PI;
    float ph_hi = (float)ph;
    float ph_lo = (float)(ph - (double)ph_hi);

    // R = exp(z*TPB_L): step between one thread's consecutive l's
    double Sd  = (double)TPB_L;
    double mag = exp(zr * Sd);
    double ang = zi * Sd;
    double Rr  = mag * cos(ang);
    double Ri  = mag * sin(ang);
    double c1  = 2.0 * Rr;              // Chebyshev coefficients
    double c2  = -(mag * mag);

    float4* base = ws + (size_t)hc * 3 * N;
    base[0*N + n] = make_float4((float)wr, (float)wi, (float)er, (float)loff);
    base[1*N + n] = make_float4(ph_hi, ph_lo, (float)c1, (float)c2);
    base[2*N + n] = make_float4((float)Rr, (float)Ri, 0.0f, 0.0f);
}

// ---------------- Kernel B: main evaluation ----------------
__global__ __launch_bounds__(TPB) void dss_main(
    const float4* __restrict__ ws,      // [C,H,3,N]
    float* __restrict__ out,            // [C,H,L]
    int H, int N, int L, int C, int chunks)
{
    __shared__ float4 sP[3 * 64];           // A[64], B[64], Cc[64]
    __shared__ float  comb[KPT][TPB_L];     // partial sums from group 1

    const int h     = blockIdx.x / chunks;
    const int chunk = blockIdx.x % chunks;
    const int c     = blockIdx.y;
    const int tid   = threadIdx.x;
    const int lt    = tid & (TPB_L - 1);    // l-lane
    const int g     = tid >> 8;             // n-group (0 or 1)

    // cooperative coefficient load: 3*N float4 = 3 KB
    if (tid < 3 * N) sP[tid] = ws[(size_t)(c*H + h) * 3 * N + tid];
    __syncthreads();

    const float4* pA = sP;
    const float4* pB = sP + N;
    const float4* pC = sP + 2 * N;

    const int lchunk = KPT * TPB_L;         // 2048 l's per block
    const int lbase  = chunk * lchunk;
    const float x0f  = (float)(lbase + lt);

    v2f acc2a[KPT], acc2b[KPT];
    #pragma unroll
    for (int k = 0; k < KPT; ++k) { acc2a[k] = (v2f)(0.0f); acc2b[k] = (v2f)(0.0f); }

    const int nbeg = g * (N / NSPLIT);
    const int nend = nbeg + (N / NSPLIT);

    for (int n = nbeg; n < nend; n += 4) {
        float4 A[4], B[4], Rv[4];
        #pragma unroll
        for (int j = 0; j < 4; ++j) { A[j] = pA[n+j]; B[j] = pB[n+j]; Rv[j] = pC[n+j]; }

        float X0[4], X1[4];
        #pragma unroll
        for (int j = 0; j < 4; ++j) {
            const float4 a = A[j]; const float4 b = B[j]; const float4 r = Rv[j];
            float x  = x0f - a.w;                          // l - loff
            float e  = __builtin_amdgcn_exp2f(a.z * x);    // |exp(zr*x)|
            float p  = b.x * x;                            // phase (rev), FMA-compensated
            float e1 = fmaf(b.x, x, -p);
            float f  = (p - floorf(p)) + fmaf(b.y, x, e1);
            float s  = vsin_rev(f);
            float co = vcos_rev(f);
            float tr = fmaf(a.x, co, -(a.y * s));
            float ti = fmaf(a.x, s,   a.y * co);
            float Tr = e * tr;                             // x_0 = Re(T)
            float Ti = e * ti;
            X0[j] = Tr;
            X1[j] = fmaf(Tr, r.x, -(Ti * r.y));            // x_1 = Re(T*R)
        }

        v2f x0a = {X0[0], X0[1]}, x1a = {X1[0], X1[1]};
        v2f x0b = {X0[2], X0[3]}, x1b = {X1[2], X1[3]};
        v2f c1a = {B[0].z, B[1].z}, c2a = {B[0].w, B[1].w};
        v2f c1b = {B[2].z, B[3].z}, c2b = {B[2].w, B[3].w};

        acc2a[0] += x0a; acc2a[1] += x1a;
        acc2b[0] += x0b; acc2b[1] += x1b;
        #pragma unroll
        for (int k = 2; k < KPT; ++k) {
            v2f ta = c2a * x0a;
            v2f xa = __builtin_elementwise_fma(c1a, x1a, ta);
            acc2a[k] += xa; x0a = x1a; x1a = xa;
            v2f tb = c2b * x0b;
            v2f xb = __builtin_elementwise_fma(c1b, x1b, tb);
            acc2b[k] += xb; x0b = x1b; x1b = xb;
        }
    }

    // per-thread totals
    float tot[KPT];
    #pragma unroll
    for (int k = 0; k < KPT; ++k)
        tot[k] = (acc2a[k].x + acc2a[k].y) + (acc2b[k].x + acc2b[k].y);

    // combine the two n-groups through LDS
    if (g == 1) {
        #pragma unroll
        for (int k = 0; k < KPT; ++k) comb[k][lt] = tot[k];
    }
    __syncthreads();
    if (g == 0) {
        float* o = out + ((size_t)c * H + h) * (size_t)L + lbase + lt;
        #pragma unroll
        for (int k = 0; k < KPT; ++k) {
            int l = lbase + lt + k * TPB_L;
            if (l < L) o[k * TPB_L] = tot[k] + comb[k][lt];
        }
    }
}

extern "C" void kernel_launch(void* const* d_in, const int* in_sizes, int n_in,
                              void* d_out, int out_size, void* d_ws, size_t ws_size,
                              hipStream_t stream) {
    // d_in[0] = L (scalar, unused on device; derived from out_size)
    const float* Lambda = (const float*)d_in[1];   // [N,2]
    const float* log_dt = (const float*)d_in[2];   // [H,2]
    const float* W      = (const float*)d_in[3];   // [C,H,N,2]
    float* out = (float*)d_out;

    const int N = in_sizes[1] / 2;                 // 64
    const int H = in_sizes[2] / 2;                 // 128
    const int C = in_sizes[3] / (2 * H * N);       // 1
    const int L = out_size / (C * H);              // 8192

    float4* ws = (float4*)d_ws;                    // [C,H,3,N] float4 = 384 KB

    const int total = C * H * N;
    dss_prep<<<(total + 255) / 256, 256, 0, stream>>>(Lambda, log_dt, W, ws, H, N, L, C);

    const int per_block = KPT * TPB_L;             // 2048
    const int chunks = (L + per_block - 1) / per_block;   // 4
    dim3 grid(H * chunks, C);
    dss_main<<<grid, TPB, 0, stream>>>(ws, out, H, N, L, C, chunks);
}

// Round 5
// 16.938 us; speedup vs baseline: 1.2347x; 1.2347x over previous
//
#include <hip/hip_runtime.h>
#include <math.h>

// DSS "softmax" kernel: K[c,h,l] = Re( sum_n Wc[c,h,n] * exp(z[h,n]*(l - loff)) )
// Round 5: single dispatch again (round 4's 2nd dispatch cost ~4us overhead).
// TPB=512: lanes [0,256) handle n in [0,32), lanes [256,512) handle n in [32,64)
// over the same 2048 l-points -> 4 waves/SIMD (vs 2 in round 3) for latency
// hiding. f64 coefficient preamble inlined (lanes < 64). Partials combined
// via LDS. Chebyshev 3-term recurrence along l unchanged (validated 2.4e-4).

#if __has_builtin(__builtin_amdgcn_sinf)
__device__ inline float vsin_rev(float x) { return __builtin_amdgcn_sinf(x); }   // sin(2*pi*x)
__device__ inline float vcos_rev(float x) { return __builtin_amdgcn_cosf(x); }   // cos(2*pi*x)
#else
__device__ inline float vsin_rev(float x) { return __sinf(x * 6.28318530717958647692f); }
__device__ inline float vcos_rev(float x) { return __cosf(x * 6.28318530717958647692f); }
#endif

typedef float v2f __attribute__((ext_vector_type(2)));

#define KPT    8     // l-values per thread
#define TPB_L  256   // threads per l-slice
#define NSPLIT 2     // n-groups per block
#define TPB    (TPB_L * NSPLIT)

__global__ __launch_bounds__(TPB) void dss_kernel(
    const float* __restrict__ Lambda,   // [N,2]
    const float* __restrict__ log_dt,   // [H,2]
    const float* __restrict__ W,        // [C,H,N,2]
    float* __restrict__ out,            // [C,H,L]
    int H, int N, int L, int C, int chunks)
{
    __shared__ float4 pA[64];   // wr, wi, er (= zr*log2e), loff
    __shared__ float4 pB[64];   // ph_hi, ph_lo (zi/2pi split), c1 (=2*Rr), c2 (=-|R|^2)
    __shared__ float2 pC[64];   // Rr, Ri
    __shared__ float  comb[KPT][TPB_L];   // partials from group 1

    const int h     = blockIdx.x / chunks;
    const int chunk = blockIdx.x % chunks;
    const int c     = blockIdx.y;
    const int tid   = threadIdx.x;
    const int lt    = tid & (TPB_L - 1);  // l-lane
    const int g     = tid >> 8;           // n-group (0 or 1)

    // ---- per-(h,n) coefficient preamble (f64, lanes < N) ----
    if (tid < N) {
        const int n = tid;
        double dt0 = exp((double)log_dt[h*2 + 0]);
        double dt1 = exp((double)log_dt[h*2 + 1]);
        double lre = (double)Lambda[n*2 + 0];
        double lim = (double)Lambda[n*2 + 1];
        double zr = dt0 * lre;
        double zi = dt1 * lim;
        bool gt0 = (lre > 0.0);
        double sgn = gt0 ? -1.0 : 1.0;
        double dnr = sgn * zr, dni = sgn * zi;
        // num = exp(dn) - 1
        double ednr  = exp(dnr);
        double num_re = ednr * cos(dni) - 1.0;
        double num_im = ednr * sin(dni);
        // den = exp(L*dn) - 1
        double Ld = (double)L;
        double eLr = exp(Ld * dnr);
        double den_re = eLr * cos(Ld * dni) - 1.0;
        double den_im = eLr * sin(Ld * dni);
        // x = den * Lam ; recip = conj(x)/(|x|^2 + eps)
        double x_re = den_re * lre - den_im * lim;
        double x_im = den_re * lim + den_im * lre;
        double inv  = 1.0 / (x_re*x_re + x_im*x_im + 1e-7);
        double r_re =  x_re * inv;
        double r_im = -x_im * inv;
        // m = num * recip
        double m_re = num_re * r_re - num_im * r_im;
        double m_im = num_re * r_im + num_im * r_re;
        // Wc = (W0 + i*W1) * m
        double w0 = (double)W[((size_t)(c*H + h)*N + n)*2 + 0];
        double w1 = (double)W[((size_t)(c*H + h)*N + n)*2 + 1];
        double wr = w0 * m_re - w1 * m_im;
        double wi = w0 * m_im + w1 * m_re;
        double loff = gt0 ? (double)(L - 1) : 0.0;

        const double LOG2E  = 1.4426950408889634074;
        const double INV2PI = 0.15915494309189533577;
        double er = zr * LOG2E;
        double ph = zi * INV2PI;
        float ph_hi = (float)ph;
        float ph_lo = (float)(ph - (double)ph_hi);

        // R = exp(z*TPB_L): step between one thread's consecutive l's
        double Sd  = (double)TPB_L;
        double mag = exp(zr * Sd);
        double ang = zi * Sd;
        double Rr  = mag * cos(ang);
        double Ri  = mag * sin(ang);
        double c1  = 2.0 * Rr;            // Chebyshev coefficients
        double c2  = -(mag * mag);

        pA[n] = make_float4((float)wr, (float)wi, (float)er, (float)loff);
        pB[n] = make_float4(ph_hi, ph_lo, (float)c1, (float)c2);
        pC[n] = make_float2((float)Rr, (float)Ri);
    }
    __syncthreads();

    // ---- main loop: KPT l-values per thread, half the n's per group ----
    const int lchunk = KPT * TPB_L;       // 2048 l's per block
    const int lbase  = chunk * lchunk;
    const float x0f  = (float)(lbase + lt);

    v2f acc2a[KPT], acc2b[KPT];
    #pragma unroll
    for (int k = 0; k < KPT; ++k) { acc2a[k] = (v2f)(0.0f); acc2b[k] = (v2f)(0.0f); }

    const int nbeg = g * (N / NSPLIT);
    const int nend = nbeg + (N / NSPLIT);

    for (int n = nbeg; n < nend; n += 4) {
        float4 A[4], B[4]; float2 Rv[4];
        #pragma unroll
        for (int j = 0; j < 4; ++j) { A[j] = pA[n+j]; B[j] = pB[n+j]; Rv[j] = pC[n+j]; }

        float X0[4], X1[4];
        #pragma unroll
        for (int j = 0; j < 4; ++j) {
            const float4 a = A[j]; const float4 b = B[j]; const float2 r = Rv[j];
            float x  = x0f - a.w;                          // l - loff
            float e  = __builtin_amdgcn_exp2f(a.z * x);    // |exp(zr*x)|
            float p  = b.x * x;                            // phase (rev), FMA-compensated
            float e1 = fmaf(b.x, x, -p);
            float f  = (p - floorf(p)) + fmaf(b.y, x, e1);
            float s  = vsin_rev(f);
            float co = vcos_rev(f);
            float tr = fmaf(a.x, co, -(a.y * s));
            float ti = fmaf(a.x, s,   a.y * co);
            float Tr = e * tr;                             // x_0 = Re(T)
            float Ti = e * ti;
            X0[j] = Tr;
            X1[j] = fmaf(Tr, r.x, -(Ti * r.y));            // x_1 = Re(T*R)
        }

        v2f x0a = {X0[0], X0[1]}, x1a = {X1[0], X1[1]};
        v2f x0b = {X0[2], X0[3]}, x1b = {X1[2], X1[3]};
        v2f c1a = {B[0].z, B[1].z}, c2a = {B[0].w, B[1].w};
        v2f c1b = {B[2].z, B[3].z}, c2b = {B[2].w, B[3].w};

        acc2a[0] += x0a; acc2a[1] += x1a;
        acc2b[0] += x0b; acc2b[1] += x1b;
        #pragma unroll
        for (int k = 2; k < KPT; ++k) {
            v2f ta = c2a * x0a;
            v2f xa = __builtin_elementwise_fma(c1a, x1a, ta);
            acc2a[k] += xa; x0a = x1a; x1a = xa;
            v2f tb = c2b * x0b;
            v2f xb = __builtin_elementwise_fma(c1b, x1b, tb);
            acc2b[k] += xb; x0b = x1b; x1b = xb;
        }
    }

    // per-thread totals
    float tot[KPT];
    #pragma unroll
    for (int k = 0; k < KPT; ++k)
        tot[k] = (acc2a[k].x + acc2a[k].y) + (acc2b[k].x + acc2b[k].y);

    // combine the two n-groups through LDS
    if (g == 1) {
        #pragma unroll
        for (int k = 0; k < KPT; ++k) comb[k][lt] = tot[k];
    }
    __syncthreads();
    if (g == 0) {
        float* o = out + ((size_t)c * H + h) * (size_t)L + lbase + lt;
        #pragma unroll
        for (int k = 0; k < KPT; ++k) {
            int l = lbase + lt + k * TPB_L;
            if (l < L) o[k * TPB_L] = tot[k] + comb[k][lt];
        }
    }
}

extern "C" void kernel_launch(void* const* d_in, const int* in_sizes, int n_in,
                              void* d_out, int out_size, void* d_ws, size_t ws_size,
                              hipStream_t stream) {
    // d_in[0] = L (scalar, unused on device; derived from out_size)
    const float* Lambda = (const float*)d_in[1];   // [N,2]
    const float* log_dt = (const float*)d_in[2];   // [H,2]
    const float* W      = (const float*)d_in[3];   // [C,H,N,2]
    float* out = (float*)d_out;

    const int N = in_sizes[1] / 2;                 // 64
    const int H = in_sizes[2] / 2;                 // 128
    const int C = in_sizes[3] / (2 * H * N);       // 1
    const int L = out_size / (C * H);              // 8192

    const int per_block = KPT * TPB_L;             // 2048
    const int chunks = (L + per_block - 1) / per_block;   // 4
    dim3 grid(H * chunks, C);
    dss_kernel<<<grid, TPB, 0, stream>>>(Lambda, log_dt, W, out, H, N, L, C, chunks);
}

// Round 6
// 15.261 us; speedup vs baseline: 1.3704x; 1.1099x over previous
//
#include <hip/hip_runtime.h>
#include <math.h>

// DSS "softmax" kernel: K[c,h,l] = Re( sum_n Wc[c,h,n] * exp(z[h,n]*(l - loff)) )
// Round 6: KPT=16 (setup amortized over 16 l's/thread, chunks=2, grid=256),
// f64 preamble split across two waves (lanes 0-63: Wc path; 64-127: phase/R
// path). Chebyshev 3-term recurrence along l (stride 256), n-split 2-way,
// partials combined via LDS. Single dispatch.

#if __has_builtin(__builtin_amdgcn_sinf)
__device__ inline float vsin_rev(float x) { return __builtin_amdgcn_sinf(x); }   // sin(2*pi*x)
__device__ inline float vcos_rev(float x) { return __builtin_amdgcn_cosf(x); }   // cos(2*pi*x)
#else
__device__ inline float vsin_rev(float x) { return __sinf(x * 6.28318530717958647692f); }
__device__ inline float vcos_rev(float x) { return __cosf(x * 6.28318530717958647692f); }
#endif

typedef float v2f __attribute__((ext_vector_type(2)));

#define KPT    16    // l-values per thread
#define TPB_L  256   // threads per l-slice
#define NSPLIT 2     // n-groups per block
#define TPB    (TPB_L * NSPLIT)

__global__ __launch_bounds__(TPB) void dss_kernel(
    const float* __restrict__ Lambda,   // [N,2]
    const float* __restrict__ log_dt,   // [H,2]
    const float* __restrict__ W,        // [C,H,N,2]
    float* __restrict__ out,            // [C,H,L]
    int H, int N, int L, int C, int chunks)
{
    __shared__ float4 pA[64];   // wr, wi, er (= zr*log2e), loff
    __shared__ float4 pB[64];   // ph_hi, ph_lo (zi/2pi split), c1 (=2*Rr), c2 (=-|R|^2)
    __shared__ float2 pC[64];   // Rr, Ri
    __shared__ float  comb[KPT][TPB_L];   // partials from group 1

    const int h     = blockIdx.x / chunks;
    const int chunk = blockIdx.x % chunks;
    const int c     = blockIdx.y;
    const int tid   = threadIdx.x;
    const int lt    = tid & (TPB_L - 1);  // l-lane
    const int g     = tid >> 8;           // n-group (0 or 1)

    // ---- per-(h,n) coefficient preamble (f64), split across two waves ----
    if (tid < N) {
        // Wave 0 path: Wc normalization (heavy: 5 exp, 4 trig, 1 div)
        const int n = tid;
        double dt0 = exp((double)log_dt[h*2 + 0]);
        double dt1 = exp((double)log_dt[h*2 + 1]);
        double lre = (double)Lambda[n*2 + 0];
        double lim = (double)Lambda[n*2 + 1];
        double zr = dt0 * lre;
        double zi = dt1 * lim;
        bool gt0 = (lre > 0.0);
        double sgn = gt0 ? -1.0 : 1.0;
        double dnr = sgn * zr, dni = sgn * zi;
        double ednr  = exp(dnr);
        double num_re = ednr * cos(dni) - 1.0;
        double num_im = ednr * sin(dni);
        double Ld = (double)L;
        double eLr = exp(Ld * dnr);
        double den_re = eLr * cos(Ld * dni) - 1.0;
        double den_im = eLr * sin(Ld * dni);
        double x_re = den_re * lre - den_im * lim;
        double x_im = den_re * lim + den_im * lre;
        double inv  = 1.0 / (x_re*x_re + x_im*x_im + 1e-7);
        double r_re =  x_re * inv;
        double r_im = -x_im * inv;
        double m_re = num_re * r_re - num_im * r_im;
        double m_im = num_re * r_im + num_im * r_re;
        double w0 = (double)W[((size_t)(c*H + h)*N + n)*2 + 0];
        double w1 = (double)W[((size_t)(c*H + h)*N + n)*2 + 1];
        double wr = w0 * m_re - w1 * m_im;
        double wi = w0 * m_im + w1 * m_re;
        double loff = gt0 ? (double)(L - 1) : 0.0;
        const double LOG2E = 1.4426950408889634074;
        double er = zr * LOG2E;
        pA[n] = make_float4((float)wr, (float)wi, (float)er, (float)loff);
    } else if (tid >= 64 && tid < 64 + N) {
        // Wave 1 path: phase split + Chebyshev/R constants (3 exp, 2 trig)
        const int n = tid - 64;
        double dt0 = exp((double)log_dt[h*2 + 0]);
        double dt1 = exp((double)log_dt[h*2 + 1]);
        double lre = (double)Lambda[n*2 + 0];
        double lim = (double)Lambda[n*2 + 1];
        double zr = dt0 * lre;
        double zi = dt1 * lim;
        const double INV2PI = 0.15915494309189533577;
        double ph = zi * INV2PI;
        float ph_hi = (float)ph;
        float ph_lo = (float)(ph - (double)ph_hi);
        // R = exp(z*TPB_L): step between one thread's consecutive l's
        double Sd  = (double)TPB_L;
        double mag = exp(zr * Sd);
        double ang = zi * Sd;
        double Rr  = mag * cos(ang);
        double Ri  = mag * sin(ang);
        double c1  = 2.0 * Rr;            // Chebyshev coefficients
        double c2  = -(mag * mag);
        pB[n] = make_float4(ph_hi, ph_lo, (float)c1, (float)c2);
        pC[n] = make_float2((float)Rr, (float)Ri);
    }
    __syncthreads();

    // ---- main loop: KPT l-values per thread, half the n's per group ----
    const int lchunk = KPT * TPB_L;       // 4096 l's per block
    const int lbase  = chunk * lchunk;
    const float x0f  = (float)(lbase + lt);

    v2f acc2a[KPT], acc2b[KPT];
    #pragma unroll
    for (int k = 0; k < KPT; ++k) { acc2a[k] = (v2f)(0.0f); acc2b[k] = (v2f)(0.0f); }

    const int nbeg = g * (N / NSPLIT);
    const int nend = nbeg + (N / NSPLIT);

    for (int n = nbeg; n < nend; n += 4) {
        float4 A[4], B[4]; float2 Rv[4];
        #pragma unroll
        for (int j = 0; j < 4; ++j) { A[j] = pA[n+j]; B[j] = pB[n+j]; Rv[j] = pC[n+j]; }

        float X0[4], X1[4];
        #pragma unroll
        for (int j = 0; j < 4; ++j) {
            const float4 a = A[j]; const float4 b = B[j]; const float2 r = Rv[j];
            float x  = x0f - a.w;                          // l - loff
            float e  = __builtin_amdgcn_exp2f(a.z * x);    // |exp(zr*x)|
            float p  = b.x * x;                            // phase (rev), FMA-compensated
            float e1 = fmaf(b.x, x, -p);
            float f  = (p - floorf(p)) + fmaf(b.y, x, e1);
            float s  = vsin_rev(f);
            float co = vcos_rev(f);
            float tr = fmaf(a.x, co, -(a.y * s));
            float ti = fmaf(a.x, s,   a.y * co);
            float Tr = e * tr;                             // x_0 = Re(T)
            float Ti = e * ti;
            X0[j] = Tr;
            X1[j] = fmaf(Tr, r.x, -(Ti * r.y));            // x_1 = Re(T*R)
        }

        v2f x0a = {X0[0], X0[1]}, x1a = {X1[0], X1[1]};
        v2f x0b = {X0[2], X0[3]}, x1b = {X1[2], X1[3]};
        v2f c1a = {B[0].z, B[1].z}, c2a = {B[0].w, B[1].w};
        v2f c1b = {B[2].z, B[3].z}, c2b = {B[2].w, B[3].w};

        acc2a[0] += x0a; acc2a[1] += x1a;
        acc2b[0] += x0b; acc2b[1] += x1b;
        #pragma unroll
        for (int k = 2; k < KPT; ++k) {
            v2f ta = c2a * x0a;
            v2f xa = __builtin_elementwise_fma(c1a, x1a, ta);
            acc2a[k] += xa; x0a = x1a; x1a = xa;
            v2f tb = c2b * x0b;
            v2f xb = __builtin_elementwise_fma(c1b, x1b, tb);
            acc2b[k] += xb; x0b = x1b; x1b = xb;
        }
    }

    // per-thread totals
    float tot[KPT];
    #pragma unroll
    for (int k = 0; k < KPT; ++k)
        tot[k] = (acc2a[k].x + acc2a[k].y) + (acc2b[k].x + acc2b[k].y);

    // combine the two n-groups through LDS
    if (g == 1) {
        #pragma unroll
        for (int k = 0; k < KPT; ++k) comb[k][lt] = tot[k];
    }
    __syncthreads();
    if (g == 0) {
        float* o = out + ((size_t)c * H + h) * (size_t)L + lbase + lt;
        #pragma unroll
        for (int k = 0; k < KPT; ++k) {
            int l = lbase + lt + k * TPB_L;
            if (l < L) o[k * TPB_L] = tot[k] + comb[k][lt];
        }
    }
}

extern "C" void kernel_launch(void* const* d_in, const int* in_sizes, int n_in,
                              void* d_out, int out_size, void* d_ws, size_t ws_size,
                              hipStream_t stream) {
    // d_in[0] = L (scalar, unused on device; derived from out_size)
    const float* Lambda = (const float*)d_in[1];   // [N,2]
    const float* log_dt = (const float*)d_in[2];   // [H,2]
    const float* W      = (const float*)d_in[3];   // [C,H,N,2]
    float* out = (float*)d_out;

    const int N = in_sizes[1] / 2;                 // 64
    const int H = in_sizes[2] / 2;                 // 128
    const int C = in_sizes[3] / (2 * H * N);       // 1
    const int L = out_size / (C * H);              // 8192

    const int per_block = KPT * TPB_L;             // 4096
    const int chunks = (L + per_block - 1) / per_block;   // 2
    dim3 grid(H * chunks, C);
    dss_kernel<<<grid, TPB, 0, stream>>>(Lambda, log_dt, W, out, H, N, L, C, chunks);
}

// Round 7
// 15.039 us; speedup vs baseline: 1.3906x; 1.0148x over previous
//
#include <hip/hip_runtime.h>
#include <math.h>

// DSS "softmax" kernel: K[c,h,l] = Re( sum_n Wc[c,h,n] * exp(z[h,n]*(l - loff)) )
// Round 7: same total work as r6 (KPT=16 Chebyshev recurrence, f64 preamble
// split over 2 waves) but repartitioned: NSPLIT=4 n-groups x TPB_L=128 l-lanes
// -> grid 512 blocks, 4096 waves = 4 waves/SIMD (r6 had 2). Accumulator banks
// merged (-32 VGPR). 4-group reduction via LDS.

#if __has_builtin(__builtin_amdgcn_sinf)
__device__ inline float vsin_rev(float x) { return __builtin_amdgcn_sinf(x); }   // sin(2*pi*x)
__device__ inline float vcos_rev(float x) { return __builtin_amdgcn_cosf(x); }   // cos(2*pi*x)
#else
__device__ inline float vsin_rev(float x) { return __sinf(x * 6.28318530717958647692f); }
__device__ inline float vcos_rev(float x) { return __cosf(x * 6.28318530717958647692f); }
#endif

typedef float v2f __attribute__((ext_vector_type(2)));

#define KPT    16    // l-values per thread
#define TPB_L  128   // l-lanes per block
#define NSPLIT 4     // n-groups per block
#define TPB    (TPB_L * NSPLIT)

__global__ __launch_bounds__(TPB, 4) void dss_kernel(
    const float* __restrict__ Lambda,   // [N,2]
    const float* __restrict__ log_dt,   // [H,2]
    const float* __restrict__ W,        // [C,H,N,2]
    float* __restrict__ out,            // [C,H,L]
    int H, int N, int L, int C, int chunks)
{
    __shared__ float4 pA[64];   // wr, wi, er (= zr*log2e), loff
    __shared__ float4 pB[64];   // ph_hi, ph_lo (zi/2pi split), c1 (=2*Rr), c2 (=-|R|^2)
    __shared__ float2 pC[64];   // Rr, Ri
    __shared__ float  comb[NSPLIT - 1][KPT][TPB_L];   // partials from groups 1..3

    const int h     = blockIdx.x / chunks;
    const int chunk = blockIdx.x % chunks;
    const int c     = blockIdx.y;
    const int tid   = threadIdx.x;
    const int lt    = tid & (TPB_L - 1);   // l-lane
    const int g     = tid / TPB_L;         // n-group (0..3)

    // ---- per-(h,n) coefficient preamble (f64), split across two waves ----
    if (tid < N) {
        // Wave 0 path: Wc normalization (heavy: exp/trig chain + div)
        const int n = tid;
        double dt0 = exp((double)log_dt[h*2 + 0]);
        double dt1 = exp((double)log_dt[h*2 + 1]);
        double lre = (double)Lambda[n*2 + 0];
        double lim = (double)Lambda[n*2 + 1];
        double zr = dt0 * lre;
        double zi = dt1 * lim;
        bool gt0 = (lre > 0.0);
        double sgn = gt0 ? -1.0 : 1.0;
        double dnr = sgn * zr, dni = sgn * zi;
        double ednr  = exp(dnr);
        double num_re = ednr * cos(dni) - 1.0;
        double num_im = ednr * sin(dni);
        double Ld = (double)L;
        double eLr = exp(Ld * dnr);
        double den_re = eLr * cos(Ld * dni) - 1.0;
        double den_im = eLr * sin(Ld * dni);
        double x_re = den_re * lre - den_im * lim;
        double x_im = den_re * lim + den_im * lre;
        double inv  = 1.0 / (x_re*x_re + x_im*x_im + 1e-7);
        double r_re =  x_re * inv;
        double r_im = -x_im * inv;
        double m_re = num_re * r_re - num_im * r_im;
        double m_im = num_re * r_im + num_im * r_re;
        double w0 = (double)W[((size_t)(c*H + h)*N + n)*2 + 0];
        double w1 = (double)W[((size_t)(c*H + h)*N + n)*2 + 1];
        double wr = w0 * m_re - w1 * m_im;
        double wi = w0 * m_im + w1 * m_re;
        double loff = gt0 ? (double)(L - 1) : 0.0;
        const double LOG2E = 1.4426950408889634074;
        double er = zr * LOG2E;
        pA[n] = make_float4((float)wr, (float)wi, (float)er, (float)loff);
    } else if (tid >= 64 && tid < 64 + N) {
        // Wave 1 path: phase split + Chebyshev/R constants
        const int n = tid - 64;
        double dt0 = exp((double)log_dt[h*2 + 0]);
        double dt1 = exp((double)log_dt[h*2 + 1]);
        double lre = (double)Lambda[n*2 + 0];
        double lim = (double)Lambda[n*2 + 1];
        double zr = dt0 * lre;
        double zi = dt1 * lim;
        const double INV2PI = 0.15915494309189533577;
        double ph = zi * INV2PI;
        float ph_hi = (float)ph;
        float ph_lo = (float)(ph - (double)ph_hi);
        // R = exp(z*TPB_L): step between one thread's consecutive l's
        double Sd  = (double)TPB_L;
        double mag = exp(zr * Sd);
        double ang = zi * Sd;
        double Rr  = mag * cos(ang);
        double Ri  = mag * sin(ang);
        double c1  = 2.0 * Rr;            // Chebyshev coefficients
        double c2  = -(mag * mag);
        pB[n] = make_float4(ph_hi, ph_lo, (float)c1, (float)c2);
        pC[n] = make_float2((float)Rr, (float)Ri);
    }
    __syncthreads();

    // ---- main loop: KPT l-values per thread, N/NSPLIT n's per group ----
    const int lchunk = KPT * TPB_L;        // 2048 l's per block
    const int lbase  = chunk * lchunk;
    const float x0f  = (float)(lbase + lt);

    v2f acc2[KPT];
    #pragma unroll
    for (int k = 0; k < KPT; ++k) acc2[k] = (v2f)(0.0f);

    const int nbeg = g * (N / NSPLIT);
    const int nend = nbeg + (N / NSPLIT);

    for (int n = nbeg; n < nend; n += 4) {
        float4 A[4], B[4]; float2 Rv[4];
        #pragma unroll
        for (int j = 0; j < 4; ++j) { A[j] = pA[n+j]; B[j] = pB[n+j]; Rv[j] = pC[n+j]; }

        float X0[4], X1[4];
        #pragma unroll
        for (int j = 0; j < 4; ++j) {
            const float4 a = A[j]; const float4 b = B[j]; const float2 r = Rv[j];
            float x  = x0f - a.w;                          // l - loff
            float e  = __builtin_amdgcn_exp2f(a.z * x);    // |exp(zr*x)|
            float p  = b.x * x;                            // phase (rev), FMA-compensated
            float e1 = fmaf(b.x, x, -p);
            float f  = (p - floorf(p)) + fmaf(b.y, x, e1);
            float s  = vsin_rev(f);
            float co = vcos_rev(f);
            float tr = fmaf(a.x, co, -(a.y * s));
            float ti = fmaf(a.x, s,   a.y * co);
            float Tr = e * tr;                             // x_0 = Re(T)
            float Ti = e * ti;
            X0[j] = Tr;
            X1[j] = fmaf(Tr, r.x, -(Ti * r.y));            // x_1 = Re(T*R)
        }

        v2f x0a = {X0[0], X0[1]}, x1a = {X1[0], X1[1]};
        v2f x0b = {X0[2], X0[3]}, x1b = {X1[2], X1[3]};
        v2f c1a = {B[0].z, B[1].z}, c2a = {B[0].w, B[1].w};
        v2f c1b = {B[2].z, B[3].z}, c2b = {B[2].w, B[3].w};

        acc2[0] += x0a + x0b;
        acc2[1] += x1a + x1b;
        #pragma unroll
        for (int k = 2; k < KPT; ++k) {
            v2f ta = c2a * x0a;
            v2f xa = __builtin_elementwise_fma(c1a, x1a, ta);
            x0a = x1a; x1a = xa;
            v2f tb = c2b * x0b;
            v2f xb = __builtin_elementwise_fma(c1b, x1b, tb);
            x0b = x1b; x1b = xb;
            acc2[k] += xa + xb;
        }
    }

    // per-thread totals
    float tot[KPT];
    #pragma unroll
    for (int k = 0; k < KPT; ++k) tot[k] = acc2[k].x + acc2[k].y;

    // combine the four n-groups through LDS
    if (g != 0) {
        #pragma unroll
        for (int k = 0; k < KPT; ++k) comb[g - 1][k][lt] = tot[k];
    }
    __syncthreads();
    if (g == 0) {
        float* o = out + ((size_t)c * H + h) * (size_t)L + lbase + lt;
        #pragma unroll
        for (int k = 0; k < KPT; ++k) {
            float v = tot[k] + comb[0][k][lt] + comb[1][k][lt] + comb[2][k][lt];
            int l = lbase + lt + k * TPB_L;
            if (l < L) o[k * TPB_L] = v;
        }
    }
}

extern "C" void kernel_launch(void* const* d_in, const int* in_sizes, int n_in,
                              void* d_out, int out_size, void* d_ws, size_t ws_size,
                              hipStream_t stream) {
    // d_in[0] = L (scalar, unused on device; derived from out_size)
    const float* Lambda = (const float*)d_in[1];   // [N,2]
    const float* log_dt = (const float*)d_in[2];   // [H,2]
    const float* W      = (const float*)d_in[3];   // [C,H,N,2]
    float* out = (float*)d_out;

    const int N = in_sizes[1] / 2;                 // 64
    const int H = in_sizes[2] / 2;                 // 128
    const int C = in_sizes[3] / (2 * H * N);       // 1
    const int L = out_size / (C * H);              // 8192

    const int per_block = KPT * TPB_L;             // 2048
    const int chunks = (L + per_block - 1) / per_block;   // 4
    dim3 grid(H * chunks, C);
    dss_kernel<<<grid, TPB, 0, stream>>>(Lambda, log_dt, W, out, H, N, L, C, chunks);
}